// Round 1
// baseline (860.863 us; speedup 1.0000x reference)
//
#include <hip/hip_runtime.h>
#include <hip/hip_bf16.h>

// GCN: 2x GCNConv(+self-loops, sym-norm) + ReLU, then Linear(64->1).
// N=100000 nodes, E=1600000 edges, IN=128, HID=64, OUT=1.
//
// Strategy:
//  - Build CSR (sorted by dst) once per call; reuse for both conv layers.
//  - t = x @ W  (dense transform first, like the reference)
//  - aggregate: one wave per node, lane = feature dim, walk CSR row.
//  - layer-2 aggregation fuses the final fc (dot with Wfc + bfc).

#define IN_DIM 128
#define HID 64

// ---------------- degree count ----------------
__global__ void count_deg(const int* __restrict__ dst, int* __restrict__ deg, int E) {
    int i = blockIdx.x * blockDim.x + threadIdx.x;
    if (i < E) atomicAdd(&deg[dst[i]], 1);
}

// ---------------- single-block exclusive scan over deg -> row_off ----------------
__global__ __launch_bounds__(1024) void scan_deg(const int* __restrict__ deg,
                                                 int* __restrict__ row_off, int n) {
    __shared__ int part[1024];
    __shared__ int total_s;
    int tid = threadIdx.x;
    int chunk = (n + 1023) / 1024;
    int s = tid * chunk;
    int e = s + chunk; if (e > n) e = n;
    int sum = 0;
    for (int i = s; i < e; ++i) sum += deg[i];
    part[tid] = sum;
    __syncthreads();
    if (tid == 0) {
        int run = 0;
        for (int i = 0; i < 1024; ++i) { int t = part[i]; part[i] = run; run += t; }
        total_s = run;
    }
    __syncthreads();
    int run = part[tid];
    for (int i = s; i < e; ++i) { row_off[i] = run; run += deg[i]; }
    if (tid == 0) row_off[n] = total_s;
}

// ---------------- per-node init: disqrt + cursor ----------------
__global__ void node_init(const int* __restrict__ deg, float* __restrict__ disqrt,
                          int* __restrict__ cursor, int n) {
    int i = blockIdx.x * blockDim.x + threadIdx.x;
    if (i < n) {
        disqrt[i] = rsqrtf((float)(deg[i] + 1));  // +1 self-loop
        cursor[i] = 0;
    }
}

// ---------------- scatter edges into CSR, precompute norm ----------------
__global__ void scatter_edges(const int* __restrict__ src, const int* __restrict__ dst,
                              const int* __restrict__ row_off, int* __restrict__ cursor,
                              const float* __restrict__ disqrt,
                              int* __restrict__ col, float* __restrict__ nrm, int E) {
    int e = blockIdx.x * blockDim.x + threadIdx.x;
    if (e < E) {
        int s = src[e], d = dst[e];
        int p = row_off[d] + atomicAdd(&cursor[d], 1);
        col[p] = s;
        nrm[p] = disqrt[s] * disqrt[d];
    }
}

// ---------------- dense transform: T[n,64] = X[n,K] @ W[K,64] ----------------
template <int K>
__global__ __launch_bounds__(256) void gemm_nodes(const float* __restrict__ X,
                                                  const float* __restrict__ W,
                                                  float* __restrict__ T, int n) {
    __shared__ float sW[K * 64];
    int tid = threadIdx.x;
    for (int i = tid; i < K * 64; i += 256) sW[i] = W[i];
    __syncthreads();
    int colc = tid & 63;
    int rg   = tid >> 6;                 // 0..3
    int base = blockIdx.x * 16 + rg * 4; // 4 nodes per thread
    if (base >= n) return;
    float acc0 = 0.f, acc1 = 0.f, acc2 = 0.f, acc3 = 0.f;
    if (base + 3 < n) {
        const float* x0 = X + (size_t)(base + 0) * K;
        const float* x1 = X + (size_t)(base + 1) * K;
        const float* x2 = X + (size_t)(base + 2) * K;
        const float* x3 = X + (size_t)(base + 3) * K;
        for (int k = 0; k < K; k += 4) {
            float4 a0 = *(const float4*)(x0 + k);
            float4 a1 = *(const float4*)(x1 + k);
            float4 a2 = *(const float4*)(x2 + k);
            float4 a3 = *(const float4*)(x3 + k);
#pragma unroll
            for (int kk = 0; kk < 4; ++kk) {
                float w = sW[(k + kk) * 64 + colc];
                acc0 += ((const float*)&a0)[kk] * w;
                acc1 += ((const float*)&a1)[kk] * w;
                acc2 += ((const float*)&a2)[kk] * w;
                acc3 += ((const float*)&a3)[kk] * w;
            }
        }
        T[(size_t)(base + 0) * 64 + colc] = acc0;
        T[(size_t)(base + 1) * 64 + colc] = acc1;
        T[(size_t)(base + 2) * 64 + colc] = acc2;
        T[(size_t)(base + 3) * 64 + colc] = acc3;
    } else {
#pragma unroll 1
        for (int j = 0; j < 4; ++j) {
            int node = base + j;
            if (node >= n) break;
            const float* xr = X + (size_t)node * K;
            float a = 0.f;
            for (int k = 0; k < K; ++k) a += xr[k] * sW[k * 64 + colc];
            T[(size_t)node * 64 + colc] = a;
        }
    }
}

// ---------------- aggregation: one wave per node ----------------
template <bool FUSE_FC>
__global__ __launch_bounds__(256) void agg_kernel(const float* __restrict__ T,
                                                  const int* __restrict__ row_off,
                                                  const int* __restrict__ col,
                                                  const float* __restrict__ nrm,
                                                  const float* __restrict__ disqrt,
                                                  const float* __restrict__ bias,
                                                  const float* __restrict__ wfc,
                                                  const float* __restrict__ bfc,
                                                  float* __restrict__ out, int n) {
    int node = blockIdx.x * 4 + (threadIdx.x >> 6);
    if (node >= n) return;
    int lane = threadIdx.x & 63;
    float dq = disqrt[node];
    float acc = T[(size_t)node * HID + lane] * (dq * dq);  // self-loop
    int beg = row_off[node], end = row_off[node + 1];
    for (int i = beg; i < end; ++i) {
        int s   = col[i];   // wave-uniform
        float w = nrm[i];   // wave-uniform
        acc += T[(size_t)s * HID + lane] * w;  // coalesced 256B gather
    }
    acc += bias[lane];
    acc = fmaxf(acc, 0.f);  // ReLU (both layers)
    if (!FUSE_FC) {
        out[(size_t)node * HID + lane] = acc;
    } else {
        float v = acc * wfc[lane];
        v += __shfl_down(v, 32, 64);
        v += __shfl_down(v, 16, 64);
        v += __shfl_down(v, 8, 64);
        v += __shfl_down(v, 4, 64);
        v += __shfl_down(v, 2, 64);
        v += __shfl_down(v, 1, 64);
        if (lane == 0) out[node] = v + bfc[0];
    }
}

extern "C" void kernel_launch(void* const* d_in, const int* in_sizes, int n_in,
                              void* d_out, int out_size, void* d_ws, size_t ws_size,
                              hipStream_t stream) {
    const float* x   = (const float*)d_in[0];
    const int*   ei  = (const int*)d_in[1];
    const float* W1  = (const float*)d_in[2];
    const float* b1  = (const float*)d_in[3];
    const float* W2  = (const float*)d_in[4];
    const float* b2  = (const float*)d_in[5];
    const float* Wfc = (const float*)d_in[6];
    const float* bfc = (const float*)d_in[7];
    float* out = (float*)d_out;

    const int N = in_sizes[0] / IN_DIM;
    const int E = in_sizes[1] / 2;
    const int* src = ei;
    const int* dst = ei + E;

    // ---- workspace carve-up (256B aligned) ----
    char* w = (char*)d_ws;
    auto alloc = [&](size_t bytes) {
        void* p = (void*)w;
        w += (bytes + 255) & ~(size_t)255;
        return p;
    };
    int*   deg     = (int*)alloc((size_t)N * 4);
    int*   row_off = (int*)alloc((size_t)(N + 1) * 4);
    int*   cursor  = (int*)alloc((size_t)N * 4);
    float* disqrt  = (float*)alloc((size_t)N * 4);
    int*   col     = (int*)alloc((size_t)E * 4);
    float* nrm     = (float*)alloc((size_t)E * 4);
    float* t1      = (float*)alloc((size_t)N * HID * 4);  // also reused as t2
    float* h1      = (float*)alloc((size_t)N * HID * 4);

    // ---- build CSR ----
    hipMemsetAsync(deg, 0, (size_t)N * 4, stream);
    count_deg<<<(E + 255) / 256, 256, 0, stream>>>(dst, deg, E);
    scan_deg<<<1, 1024, 0, stream>>>(deg, row_off, N);
    node_init<<<(N + 255) / 256, 256, 0, stream>>>(deg, disqrt, cursor, N);
    scatter_edges<<<(E + 255) / 256, 256, 0, stream>>>(src, dst, row_off, cursor,
                                                       disqrt, col, nrm, E);

    // ---- layer 1 ----
    gemm_nodes<IN_DIM><<<(N + 15) / 16, 256, 0, stream>>>(x, W1, t1, N);
    agg_kernel<false><<<(N + 3) / 4, 256, 0, stream>>>(t1, row_off, col, nrm, disqrt,
                                                       b1, nullptr, nullptr, h1, N);

    // ---- layer 2 + fused fc ----
    gemm_nodes<HID><<<(N + 15) / 16, 256, 0, stream>>>(h1, W2, t1, N);
    agg_kernel<true><<<(N + 3) / 4, 256, 0, stream>>>(t1, row_off, col, nrm, disqrt,
                                                      b2, Wfc, bfc, out, N);
}

// Round 2
// 529.864 us; speedup vs baseline: 1.6247x; 1.6247x over previous
//
#include <hip/hip_runtime.h>
#include <hip/hip_bf16.h>

// GCN: 2x GCNConv(+self-loops, sym-norm) + ReLU, then Linear(64->1).
// N=100000 nodes, E=1600000 edges, IN=128, HID=64, OUT=1.
//
//  - CSR build (sorted by dst) once per call; multi-block scan (R1 fix:
//    single-block scan was 168us @ 0.16% occupancy).
//  - t = x @ W dense transform first, then per-node wave aggregation.
//  - agg: edge loop unrolled x4 with readfirstlane'd source index so the
//    gather base is scalar (SGPR) and 4 gathers are in flight per wave.

#define IN_DIM 128
#define HID 64

// ---------------- degree count ----------------
__global__ void count_deg(const int* __restrict__ dst, int* __restrict__ deg, int E) {
    int i = blockIdx.x * blockDim.x + threadIdx.x;
    if (i < E) atomicAdd(&deg[dst[i]], 1);
}

// ---------------- multi-block exclusive scan over deg -> row_off ----------------
// pass1: per-block (256 elems) reduce -> bsum[b]
__global__ __launch_bounds__(256) void scan_pass1(const int* __restrict__ deg,
                                                  int* __restrict__ bsum, int n) {
    int i = blockIdx.x * 256 + threadIdx.x;
    int v = (i < n) ? deg[i] : 0;
#pragma unroll
    for (int o = 32; o; o >>= 1) v += __shfl_down(v, o, 64);
    __shared__ int ws[4];
    int lane = threadIdx.x & 63, wid = threadIdx.x >> 6;
    if (lane == 0) ws[wid] = v;
    __syncthreads();
    if (threadIdx.x == 0) bsum[blockIdx.x] = ws[0] + ws[1] + ws[2] + ws[3];
}

// pass2: single block scans block sums (nb <= 512; nb=391 for N=100000)
__global__ __launch_bounds__(512) void scan_pass2(const int* __restrict__ bsum,
                                                  int* __restrict__ boff,
                                                  int* __restrict__ row_off, // writes row_off[n]
                                                  int nb, int n) {
    __shared__ int s[512];
    int t = threadIdx.x;
    int v = (t < nb) ? bsum[t] : 0;
    s[t] = v;
    __syncthreads();
#pragma unroll
    for (int o = 1; o < 512; o <<= 1) {
        int add = (t >= o) ? s[t - o] : 0;
        __syncthreads();
        s[t] += add;
        __syncthreads();
    }
    if (t < nb) boff[t] = s[t] - v;  // exclusive
    if (t == nb - 1) row_off[n] = s[t];
}

// pass3: block-local exclusive scan + block offset -> row_off; fuses node_init
__global__ __launch_bounds__(256) void scan_pass3(const int* __restrict__ deg,
                                                  const int* __restrict__ boff,
                                                  int* __restrict__ row_off,
                                                  float* __restrict__ disqrt,
                                                  int* __restrict__ cursor, int n) {
    __shared__ int s[256];
    int i = blockIdx.x * 256 + threadIdx.x;
    int t = threadIdx.x;
    int d = (i < n) ? deg[i] : 0;
    s[t] = d;
    __syncthreads();
#pragma unroll
    for (int o = 1; o < 256; o <<= 1) {
        int add = (t >= o) ? s[t - o] : 0;
        __syncthreads();
        s[t] += add;
        __syncthreads();
    }
    if (i < n) {
        row_off[i] = s[t] - d + boff[blockIdx.x];
        disqrt[i] = rsqrtf((float)(d + 1));  // +1 self-loop
        cursor[i] = 0;
    }
}

// ---------------- scatter edges into CSR, precompute norm ----------------
__global__ void scatter_edges(const int* __restrict__ src, const int* __restrict__ dst,
                              const int* __restrict__ row_off, int* __restrict__ cursor,
                              const float* __restrict__ disqrt,
                              int* __restrict__ col, float* __restrict__ nrm, int E) {
    int e = blockIdx.x * blockDim.x + threadIdx.x;
    if (e < E) {
        int s = src[e], d = dst[e];
        int p = row_off[d] + atomicAdd(&cursor[d], 1);
        col[p] = s;
        nrm[p] = disqrt[s] * disqrt[d];
    }
}

// ---------------- dense transform: T[n,64] = X[n,K] @ W[K,64] ----------------
template <int K>
__global__ __launch_bounds__(256) void gemm_nodes(const float* __restrict__ X,
                                                  const float* __restrict__ W,
                                                  float* __restrict__ T, int n) {
    __shared__ float sW[K * 64];
    int tid = threadIdx.x;
    for (int i = tid; i < K * 64; i += 256) sW[i] = W[i];
    __syncthreads();
    int colc = tid & 63;
    int rg   = tid >> 6;                 // 0..3
    int base = blockIdx.x * 16 + rg * 4; // 4 nodes per thread
    if (base >= n) return;
    float acc0 = 0.f, acc1 = 0.f, acc2 = 0.f, acc3 = 0.f;
    if (base + 3 < n) {
        const float* x0 = X + (size_t)(base + 0) * K;
        const float* x1 = X + (size_t)(base + 1) * K;
        const float* x2 = X + (size_t)(base + 2) * K;
        const float* x3 = X + (size_t)(base + 3) * K;
        for (int k = 0; k < K; k += 4) {
            float4 a0 = *(const float4*)(x0 + k);
            float4 a1 = *(const float4*)(x1 + k);
            float4 a2 = *(const float4*)(x2 + k);
            float4 a3 = *(const float4*)(x3 + k);
#pragma unroll
            for (int kk = 0; kk < 4; ++kk) {
                float w = sW[(k + kk) * 64 + colc];
                acc0 += ((const float*)&a0)[kk] * w;
                acc1 += ((const float*)&a1)[kk] * w;
                acc2 += ((const float*)&a2)[kk] * w;
                acc3 += ((const float*)&a3)[kk] * w;
            }
        }
        T[(size_t)(base + 0) * 64 + colc] = acc0;
        T[(size_t)(base + 1) * 64 + colc] = acc1;
        T[(size_t)(base + 2) * 64 + colc] = acc2;
        T[(size_t)(base + 3) * 64 + colc] = acc3;
    } else {
#pragma unroll 1
        for (int j = 0; j < 4; ++j) {
            int node = base + j;
            if (node >= n) break;
            const float* xr = X + (size_t)node * K;
            float a = 0.f;
            for (int k = 0; k < K; ++k) a += xr[k] * sW[k * 64 + colc];
            T[(size_t)node * 64 + colc] = a;
        }
    }
}

// ---------------- aggregation: one wave per node, 4 edges in flight ----------------
template <bool FUSE_FC>
__global__ __launch_bounds__(256) void agg_kernel(const float* __restrict__ T,
                                                  const int* __restrict__ row_off,
                                                  const int* __restrict__ col,
                                                  const float* __restrict__ nrm,
                                                  const float* __restrict__ disqrt,
                                                  const float* __restrict__ bias,
                                                  const float* __restrict__ wfc,
                                                  const float* __restrict__ bfc,
                                                  float* __restrict__ out, int n) {
    int node = blockIdx.x * 4 + (threadIdx.x >> 6);
    if (node >= n) return;
    int lane = threadIdx.x & 63;
    float dq = disqrt[node];
    float acc = T[(size_t)node * HID + lane] * (dq * dq);  // self-loop
    int beg = row_off[node], end = row_off[node + 1];
    beg = __builtin_amdgcn_readfirstlane(beg);
    end = __builtin_amdgcn_readfirstlane(end);
    int i = beg;
    for (; i + 4 <= end; i += 4) {
        // wave-uniform metadata; readfirstlane puts gather bases in SGPRs
        int s0 = __builtin_amdgcn_readfirstlane(col[i + 0]);
        int s1 = __builtin_amdgcn_readfirstlane(col[i + 1]);
        int s2 = __builtin_amdgcn_readfirstlane(col[i + 2]);
        int s3 = __builtin_amdgcn_readfirstlane(col[i + 3]);
        float w0 = nrm[i + 0], w1 = nrm[i + 1], w2 = nrm[i + 2], w3 = nrm[i + 3];
        float g0 = T[(size_t)s0 * HID + lane];
        float g1 = T[(size_t)s1 * HID + lane];
        float g2 = T[(size_t)s2 * HID + lane];
        float g3 = T[(size_t)s3 * HID + lane];
        acc += g0 * w0;
        acc += g1 * w1;
        acc += g2 * w2;
        acc += g3 * w3;
    }
    for (; i < end; ++i) {
        int s = __builtin_amdgcn_readfirstlane(col[i]);
        float w = nrm[i];
        acc += T[(size_t)s * HID + lane] * w;
    }
    acc += bias[lane];
    acc = fmaxf(acc, 0.f);  // ReLU (both layers)
    if (!FUSE_FC) {
        out[(size_t)node * HID + lane] = acc;
    } else {
        float v = acc * wfc[lane];
        v += __shfl_down(v, 32, 64);
        v += __shfl_down(v, 16, 64);
        v += __shfl_down(v, 8, 64);
        v += __shfl_down(v, 4, 64);
        v += __shfl_down(v, 2, 64);
        v += __shfl_down(v, 1, 64);
        if (lane == 0) out[node] = v + bfc[0];
    }
}

extern "C" void kernel_launch(void* const* d_in, const int* in_sizes, int n_in,
                              void* d_out, int out_size, void* d_ws, size_t ws_size,
                              hipStream_t stream) {
    const float* x   = (const float*)d_in[0];
    const int*   ei  = (const int*)d_in[1];
    const float* W1  = (const float*)d_in[2];
    const float* b1  = (const float*)d_in[3];
    const float* W2  = (const float*)d_in[4];
    const float* b2  = (const float*)d_in[5];
    const float* Wfc = (const float*)d_in[6];
    const float* bfc = (const float*)d_in[7];
    float* out = (float*)d_out;

    const int N = in_sizes[0] / IN_DIM;
    const int E = in_sizes[1] / 2;
    const int* src = ei;
    const int* dst = ei + E;
    const int NB = (N + 255) / 256;  // scan blocks (must be <= 512)

    // ---- workspace carve-up (256B aligned) ----
    char* w = (char*)d_ws;
    auto alloc = [&](size_t bytes) {
        void* p = (void*)w;
        w += (bytes + 255) & ~(size_t)255;
        return p;
    };
    int*   deg     = (int*)alloc((size_t)N * 4);
    int*   row_off = (int*)alloc((size_t)(N + 1) * 4);
    int*   cursor  = (int*)alloc((size_t)N * 4);
    float* disqrt  = (float*)alloc((size_t)N * 4);
    int*   bsum    = (int*)alloc(512 * 4);
    int*   boff    = (int*)alloc(512 * 4);
    int*   col     = (int*)alloc((size_t)E * 4);
    float* nrm     = (float*)alloc((size_t)E * 4);
    float* t1      = (float*)alloc((size_t)N * HID * 4);  // also reused as t2
    float* h1      = (float*)alloc((size_t)N * HID * 4);

    // ---- build CSR ----
    hipMemsetAsync(deg, 0, (size_t)N * 4, stream);
    count_deg<<<(E + 255) / 256, 256, 0, stream>>>(dst, deg, E);
    scan_pass1<<<NB, 256, 0, stream>>>(deg, bsum, N);
    scan_pass2<<<1, 512, 0, stream>>>(bsum, boff, row_off, NB, N);
    scan_pass3<<<NB, 256, 0, stream>>>(deg, boff, row_off, disqrt, cursor, N);
    scatter_edges<<<(E + 255) / 256, 256, 0, stream>>>(src, dst, row_off, cursor,
                                                       disqrt, col, nrm, E);

    // ---- layer 1 ----
    gemm_nodes<IN_DIM><<<(N + 15) / 16, 256, 0, stream>>>(x, W1, t1, N);
    agg_kernel<false><<<(N + 3) / 4, 256, 0, stream>>>(t1, row_off, col, nrm, disqrt,
                                                       b1, nullptr, nullptr, h1, N);

    // ---- layer 2 + fused fc ----
    gemm_nodes<HID><<<(N + 15) / 16, 256, 0, stream>>>(h1, W2, t1, N);
    agg_kernel<true><<<(N + 3) / 4, 256, 0, stream>>>(t1, row_off, col, nrm, disqrt,
                                                      b2, Wfc, bfc, out, N);
}

// Round 3
// 406.435 us; speedup vs baseline: 2.1181x; 1.3037x over previous
//
#include <hip/hip_runtime.h>
#include <hip/hip_bf16.h>

// GCN: 2x GCNConv(+self-loops, sym-norm) + ReLU, then Linear(64->1).
// N=100000 nodes, E=1600000 edges, IN=128, HID=64, OUT=1.
//
//  - CSR build (sorted by dst) once per call; multi-block scan.
//  - R2 fix: gemm was wave-broadcast-load latency-bound (29% VALU, 5% HBM).
//    Now: 64x64 tile, K-chunk 32, x staged transposed in LDS, 4x4 register
//    blocking -> 2 ds_read_b128 + 16 FMA per thread per k.
//  - agg: one wave per node, edge loop unrolled x8, scalarized gather base.

#define IN_DIM 128
#define HID 64

// ---------------- degree count ----------------
__global__ void count_deg(const int* __restrict__ dst, int* __restrict__ deg, int E) {
    int i = blockIdx.x * blockDim.x + threadIdx.x;
    if (i < E) atomicAdd(&deg[dst[i]], 1);
}

// ---------------- multi-block exclusive scan over deg -> row_off ----------------
__global__ __launch_bounds__(256) void scan_pass1(const int* __restrict__ deg,
                                                  int* __restrict__ bsum, int n) {
    int i = blockIdx.x * 256 + threadIdx.x;
    int v = (i < n) ? deg[i] : 0;
#pragma unroll
    for (int o = 32; o; o >>= 1) v += __shfl_down(v, o, 64);
    __shared__ int ws[4];
    int lane = threadIdx.x & 63, wid = threadIdx.x >> 6;
    if (lane == 0) ws[wid] = v;
    __syncthreads();
    if (threadIdx.x == 0) bsum[blockIdx.x] = ws[0] + ws[1] + ws[2] + ws[3];
}

__global__ __launch_bounds__(512) void scan_pass2(const int* __restrict__ bsum,
                                                  int* __restrict__ boff,
                                                  int* __restrict__ row_off,
                                                  int nb, int n) {
    __shared__ int s[512];
    int t = threadIdx.x;
    int v = (t < nb) ? bsum[t] : 0;
    s[t] = v;
    __syncthreads();
#pragma unroll
    for (int o = 1; o < 512; o <<= 1) {
        int add = (t >= o) ? s[t - o] : 0;
        __syncthreads();
        s[t] += add;
        __syncthreads();
    }
    if (t < nb) boff[t] = s[t] - v;  // exclusive
    if (t == nb - 1) row_off[n] = s[t];
}

__global__ __launch_bounds__(256) void scan_pass3(const int* __restrict__ deg,
                                                  const int* __restrict__ boff,
                                                  int* __restrict__ row_off,
                                                  float* __restrict__ disqrt,
                                                  int* __restrict__ cursor, int n) {
    __shared__ int s[256];
    int i = blockIdx.x * 256 + threadIdx.x;
    int t = threadIdx.x;
    int d = (i < n) ? deg[i] : 0;
    s[t] = d;
    __syncthreads();
#pragma unroll
    for (int o = 1; o < 256; o <<= 1) {
        int add = (t >= o) ? s[t - o] : 0;
        __syncthreads();
        s[t] += add;
        __syncthreads();
    }
    if (i < n) {
        row_off[i] = s[t] - d + boff[blockIdx.x];
        disqrt[i] = rsqrtf((float)(d + 1));  // +1 self-loop
        cursor[i] = 0;
    }
}

// ---------------- scatter edges into CSR, precompute norm ----------------
__global__ void scatter_edges(const int* __restrict__ src, const int* __restrict__ dst,
                              const int* __restrict__ row_off, int* __restrict__ cursor,
                              const float* __restrict__ disqrt,
                              int* __restrict__ col, float* __restrict__ nrm, int E) {
    int e = blockIdx.x * blockDim.x + threadIdx.x;
    if (e < E) {
        int s = src[e], d = dst[e];
        int p = row_off[d] + atomicAdd(&cursor[d], 1);
        col[p] = s;
        nrm[p] = disqrt[s] * disqrt[d];
    }
}

// ---------------- tiled GEMM: T[n,64] = X[n,K] @ W[K,64] ----------------
// 64 nodes x 64 cols per block, K-chunks of 32, 4x4 register blocking.
template <int K>
__global__ __launch_bounds__(256) void gemm_tile(const float* __restrict__ X,
                                                 const float* __restrict__ W,
                                                 float* __restrict__ T, int n) {
    __shared__ float xs[32][68];   // [k][m]; stride 68 floats keeps rows 16B-aligned
    __shared__ float ws[32][64];   // [k][c]
    const int tid  = threadIdx.x;
    const int nIdx = tid & 15;     // cols 4*nIdx..+3
    const int mIdx = tid >> 4;     // nodes 4*mIdx..+3
    const int m0   = blockIdx.x * 64;
    float acc[4][4] = {};
    for (int kc = 0; kc < K; kc += 32) {
        // stage X chunk transposed: 64 rows x 32 k  (512 float4, 2/thread)
        int f = tid;
#pragma unroll
        for (int i = 0; i < 2; ++i, f += 256) {
            int r  = f >> 3;           // 0..63
            int kq = f & 7;            // float4 within chunk
            int row = m0 + r;
            float4 g = make_float4(0.f, 0.f, 0.f, 0.f);
            if (row < n) g = *(const float4*)(X + (size_t)row * K + kc + 4 * kq);
            xs[4 * kq + 0][r] = g.x;
            xs[4 * kq + 1][r] = g.y;
            xs[4 * kq + 2][r] = g.z;
            xs[4 * kq + 3][r] = g.w;
        }
        // stage W chunk: 32 k x 64 cols (512 float4, 2/thread)
        f = tid;
#pragma unroll
        for (int i = 0; i < 2; ++i, f += 256) {
            int kk = f >> 4;           // 0..31
            int cq = f & 15;           // 0..15
            *(float4*)&ws[kk][4 * cq] =
                *(const float4*)(W + (size_t)(kc + kk) * 64 + 4 * cq);
        }
        __syncthreads();
#pragma unroll 4
        for (int k = 0; k < 32; ++k) {
            float4 a = *(const float4*)&xs[k][4 * mIdx];
            float4 b = *(const float4*)&ws[k][4 * nIdx];
            const float* ap = (const float*)&a;
            const float* bp = (const float*)&b;
#pragma unroll
            for (int mi = 0; mi < 4; ++mi)
#pragma unroll
                for (int ni = 0; ni < 4; ++ni)
                    acc[mi][ni] += ap[mi] * bp[ni];
        }
        __syncthreads();
    }
#pragma unroll
    for (int mi = 0; mi < 4; ++mi) {
        int row = m0 + 4 * mIdx + mi;
        if (row < n)
            *(float4*)(T + (size_t)row * 64 + 4 * nIdx) =
                make_float4(acc[mi][0], acc[mi][1], acc[mi][2], acc[mi][3]);
    }
}

// ---------------- aggregation: one wave per node, 8 edges in flight ----------------
template <bool FUSE_FC>
__global__ __launch_bounds__(256) void agg_kernel(const float* __restrict__ T,
                                                  const int* __restrict__ row_off,
                                                  const int* __restrict__ col,
                                                  const float* __restrict__ nrm,
                                                  const float* __restrict__ disqrt,
                                                  const float* __restrict__ bias,
                                                  const float* __restrict__ wfc,
                                                  const float* __restrict__ bfc,
                                                  float* __restrict__ out, int n) {
    int node = blockIdx.x * 4 + (threadIdx.x >> 6);
    if (node >= n) return;
    int lane = threadIdx.x & 63;
    float dq = disqrt[node];
    float acc = T[(size_t)node * HID + lane] * (dq * dq);  // self-loop
    int beg = row_off[node], end = row_off[node + 1];
    beg = __builtin_amdgcn_readfirstlane(beg);
    end = __builtin_amdgcn_readfirstlane(end);
    int i = beg;
    for (; i + 8 <= end; i += 8) {
        int s0 = __builtin_amdgcn_readfirstlane(col[i + 0]);
        int s1 = __builtin_amdgcn_readfirstlane(col[i + 1]);
        int s2 = __builtin_amdgcn_readfirstlane(col[i + 2]);
        int s3 = __builtin_amdgcn_readfirstlane(col[i + 3]);
        int s4 = __builtin_amdgcn_readfirstlane(col[i + 4]);
        int s5 = __builtin_amdgcn_readfirstlane(col[i + 5]);
        int s6 = __builtin_amdgcn_readfirstlane(col[i + 6]);
        int s7 = __builtin_amdgcn_readfirstlane(col[i + 7]);
        float w0 = nrm[i + 0], w1 = nrm[i + 1], w2 = nrm[i + 2], w3 = nrm[i + 3];
        float w4 = nrm[i + 4], w5 = nrm[i + 5], w6 = nrm[i + 6], w7 = nrm[i + 7];
        float g0 = T[(size_t)s0 * HID + lane];
        float g1 = T[(size_t)s1 * HID + lane];
        float g2 = T[(size_t)s2 * HID + lane];
        float g3 = T[(size_t)s3 * HID + lane];
        float g4 = T[(size_t)s4 * HID + lane];
        float g5 = T[(size_t)s5 * HID + lane];
        float g6 = T[(size_t)s6 * HID + lane];
        float g7 = T[(size_t)s7 * HID + lane];
        acc += g0 * w0; acc += g1 * w1; acc += g2 * w2; acc += g3 * w3;
        acc += g4 * w4; acc += g5 * w5; acc += g6 * w6; acc += g7 * w7;
    }
    for (; i < end; ++i) {
        int s = __builtin_amdgcn_readfirstlane(col[i]);
        float w = nrm[i];
        acc += T[(size_t)s * HID + lane] * w;
    }
    acc += bias[lane];
    acc = fmaxf(acc, 0.f);  // ReLU (both layers)
    if (!FUSE_FC) {
        out[(size_t)node * HID + lane] = acc;
    } else {
        float v = acc * wfc[lane];
        v += __shfl_down(v, 32, 64);
        v += __shfl_down(v, 16, 64);
        v += __shfl_down(v, 8, 64);
        v += __shfl_down(v, 4, 64);
        v += __shfl_down(v, 2, 64);
        v += __shfl_down(v, 1, 64);
        if (lane == 0) out[node] = v + bfc[0];
    }
}

extern "C" void kernel_launch(void* const* d_in, const int* in_sizes, int n_in,
                              void* d_out, int out_size, void* d_ws, size_t ws_size,
                              hipStream_t stream) {
    const float* x   = (const float*)d_in[0];
    const int*   ei  = (const int*)d_in[1];
    const float* W1  = (const float*)d_in[2];
    const float* b1  = (const float*)d_in[3];
    const float* W2  = (const float*)d_in[4];
    const float* b2  = (const float*)d_in[5];
    const float* Wfc = (const float*)d_in[6];
    const float* bfc = (const float*)d_in[7];
    float* out = (float*)d_out;

    const int N = in_sizes[0] / IN_DIM;
    const int E = in_sizes[1] / 2;
    const int* src = ei;
    const int* dst = ei + E;
    const int NB = (N + 255) / 256;  // scan blocks (must be <= 512)

    // ---- workspace carve-up (256B aligned) ----
    char* w = (char*)d_ws;
    auto alloc = [&](size_t bytes) {
        void* p = (void*)w;
        w += (bytes + 255) & ~(size_t)255;
        return p;
    };
    int*   deg     = (int*)alloc((size_t)N * 4);
    int*   row_off = (int*)alloc((size_t)(N + 1) * 4);
    int*   cursor  = (int*)alloc((size_t)N * 4);
    float* disqrt  = (float*)alloc((size_t)N * 4);
    int*   bsum    = (int*)alloc(512 * 4);
    int*   boff    = (int*)alloc(512 * 4);
    int*   col     = (int*)alloc((size_t)E * 4);
    float* nrm     = (float*)alloc((size_t)E * 4);
    float* t1      = (float*)alloc((size_t)N * HID * 4);  // also reused as t2
    float* h1      = (float*)alloc((size_t)N * HID * 4);

    // ---- build CSR ----
    hipMemsetAsync(deg, 0, (size_t)N * 4, stream);
    count_deg<<<(E + 255) / 256, 256, 0, stream>>>(dst, deg, E);
    scan_pass1<<<NB, 256, 0, stream>>>(deg, bsum, N);
    scan_pass2<<<1, 512, 0, stream>>>(bsum, boff, row_off, NB, N);
    scan_pass3<<<NB, 256, 0, stream>>>(deg, boff, row_off, disqrt, cursor, N);
    scatter_edges<<<(E + 255) / 256, 256, 0, stream>>>(src, dst, row_off, cursor,
                                                       disqrt, col, nrm, E);

    // ---- layer 1 ----
    gemm_tile<IN_DIM><<<(N + 63) / 64, 256, 0, stream>>>(x, W1, t1, N);
    agg_kernel<false><<<(N + 3) / 4, 256, 0, stream>>>(t1, row_off, col, nrm, disqrt,
                                                       b1, nullptr, nullptr, h1, N);

    // ---- layer 2 + fused fc ----
    gemm_tile<HID><<<(N + 63) / 64, 256, 0, stream>>>(h1, W2, t1, N);
    agg_kernel<true><<<(N + 3) / 4, 256, 0, stream>>>(t1, row_off, col, nrm, disqrt,
                                                      b2, Wfc, bfc, out, N);
}